// Round 15
// baseline (61.788 us; speedup 1.0000x reference)
//
#include <hip/hip_runtime.h>

static constexpr int T_LEN = 1024;
static constexpr int KTAG = 24;
static constexpr int MAT = 576;      // 24*24
static constexpr int START_TAG = 22;
static constexpr int END_TAG = 23;
static constexpr int BATCH = 128;
static constexpr int CHUNK = 32;
static constexpr int NCHUNK = 32;

static constexpr float LOG2E = 1.4426950408889634f;
static constexpr float LN2   = 0.6931471805599453f;

typedef short  bf16x8 __attribute__((ext_vector_type(8)));
typedef float  f32x16 __attribute__((ext_vector_type(16)));

__device__ __forceinline__ float fexp2(float x) { return __builtin_amdgcn_exp2f(x); }
__device__ __forceinline__ float flog2(float x) { return __builtin_amdgcn_logf(x); }

// fp32 -> bf16 bits, round-to-nearest-even (branchless; inputs finite positive).
// NOTE: hand-written v_cvt_pk_bf16_f32 asm was convicted of the R5/R6 NaNs — keep f2bf.
__device__ __forceinline__ unsigned int f2bf(float x) {
  unsigned int u = __float_as_uint(x);
  u += 0x7FFFu + ((u >> 16) & 1u);
  return u >> 16;
}

// ---------------------------------------------------------------------------
// Phase A (MFMA): per-(batch,chunk) wave computes Q = W_{t0+n-1}^T ... W_{t0}^T
// via pairs of mfma_f32_32x32x16_bf16, state Q as B-operand (verified k-slot
// permutation: slot(hd,e) -> k=(e&3)+8*(e>>2)+4*hd, +16 for mfma2).
// Antithetic pairs (R10-verified): (b,c) <-> (127-b,31-c), ~32 steps/pair.
// R14: rescale every 2nd step only (CONVF at odd steps, CONVL at even) —
// removes readfirstlane+SALU+16 muls from half the serial D->B conversions.
// Growth bound: <=2^26 per 2-step window on top of [1,2) — fp32/bf16 safe;
// 2^-dd rescale exact, so numerics relative-precision-identical to R10.
// (R12: CHUNK=16 regressed; R13: LDS streaming regressed — keep R10 loads.)
// ---------------------------------------------------------------------------
__global__ __launch_bounds__(256) void chunkprod_kernel(
    const float* __restrict__ scores, const int* __restrict__ targets,
    const int* __restrict__ lengths,
    float* __restrict__ wsP, int* __restrict__ wsE, float* __restrict__ wsG)
{
  const int widx = threadIdx.x >> 6;
  const int lane = threadIdx.x & 63;
  const int i = blockIdx.x * 4 + widx;
  const int pr = i >> 1;                 // pair id
  const int anti = i & 1;
  const int b0i = pr >> 4;
  const int c0i = pr & 15;
  const int b = anti ? (127 - b0i) : b0i;
  const int c = anti ? (31 - c0i) : c0i;
  const int len = lengths[b];
  const int t0 = 1 + c * CHUNK;
  if (t0 >= len) return;                 // wave-uniform exit; slot never read
  const int n = min(CHUNK, len - t0);
  const int hd = lane >> 5;
  const int m = lane & 31;
  const int mc = m < KTAG ? m : KTAG - 1;   // address clamp for padding rows
  const float* sb = scores + (size_t)b * T_LEN * MAT;

  // fused gold partial: t in [t0, t0+n) -> wsG slot (no atomic)
  {
    float gs = 0.f;
    if (lane < n) {
      int t = t0 + lane;
      gs = sb[(size_t)t * MAT + targets[b * T_LEN + t]];
    }
    #pragma unroll
    for (int off = 1; off < 64; off <<= 1) gs += __shfl_xor(gs, off, 64);
    if (lane == 0) wsG[b * NCHUNK + c] = gs;
  }

  // A-load offsets (dwords) under the k-permutation
  int off1[8], off2[4];
  #pragma unroll
  for (int e = 0; e < 8; ++e) {
    int k = (e & 3) + 8 * (e >> 2) + 4 * hd;         // mfma1 global k
    off1[e] = k * KTAG + mc;
  }
  #pragma unroll
  for (int e = 0; e < 4; ++e) {
    int k = 16 + e + 4 * hd;                         // mfma2 global k (<24)
    off2[e] = k * KTAG + mc;
  }

  float b0r[12], b1r[12], b2r[12], b3r[12];
  auto LOADA = [&](float (&buf)[12], int step) {
    const float* pb = sb + (size_t)(t0 + step) * MAT;
    #pragma unroll
    for (int e = 0; e < 8; ++e) buf[e] = pb[off1[e]];
    #pragma unroll
    for (int e = 0; e < 4; ++e) buf[8 + e] = pb[off2[e]];
  };

  // B state: 8 packed uints (2 bf16 each). Init = identity under g().
  unsigned int p[8];
  #pragma unroll
  for (int r = 0; r < 8; ++r) {
    int rlo = ((2 * r) & 3) + 8 * ((2 * r) >> 2) + 4 * hd;  // rows (rlo, rlo+1)
    unsigned int v = 0;
    if (m == rlo)     v |= 0x3F80u;
    if (m == rlo + 1) v |= (0x3F80u << 16);
    p[r] = v;
  }

  int E = 0;

  auto STEPM = [&](const float (&buf)[12]) -> f32x16 {
    float av[12];
    #pragma unroll
    for (int q = 0; q < 12; ++q) av[q] = fexp2(buf[q] * LOG2E);  // loads-only dep
    bf16x8 a1, a2;
    #pragma unroll
    for (int e = 0; e < 8; ++e) a1[e] = (short)f2bf(av[e]);
    #pragma unroll
    for (int e = 0; e < 4; ++e) a2[e] = (short)f2bf(av[8 + e]);
    #pragma unroll
    for (int e = 4; e < 8; ++e) a2[e] = 0;                   // k>=24 padding
    union { unsigned int u[4]; bf16x8 v; } B1, B2;
    B1.u[0] = p[0]; B1.u[1] = p[1]; B1.u[2] = p[2]; B1.u[3] = p[3];
    B2.u[0] = p[4]; B2.u[1] = p[5]; B2.u[2] = p[6]; B2.u[3] = p[7];
    f32x16 d = {};
    d = __builtin_amdgcn_mfma_f32_32x32x16_bf16(a1, B1.v, d, 0, 0, 0);
    d = __builtin_amdgcn_mfma_f32_32x32x16_bf16(a2, B2.v, d, 0, 0, 0);
    return d;
  };

  auto CONVL = [&](const f32x16& d) {     // lite: no rescale (even steps)
    #pragma unroll
    for (int r = 0; r < 8; ++r)
      p[r] = (f2bf(d[2 * r + 1]) << 16) | f2bf(d[2 * r]);
  };
  auto CONVF = [&](const f32x16& d) {     // full: exact 2^-dd rescale (odd steps)
    int rb = __builtin_amdgcn_readfirstlane(__float_as_int(d[0]));
    int dd = ((rb >> 23) & 255) - 127;
    E += dd;
    float sc = __int_as_float((127 - dd) << 23);
    #pragma unroll
    for (int r = 0; r < 8; ++r)
      p[r] = (f2bf(d[2 * r + 1] * sc) << 16) | f2bf(d[2 * r] * sc);
  };

  LOADA(b0r, 0);
  LOADA(b1r, n > 1 ? 1 : 0);
  LOADA(b2r, n > 2 ? 2 : 0);
  LOADA(b3r, n > 3 ? 3 : 0);
  f32x16 z;
  int s = 0;
  for (;;) {
    z = STEPM(b0r);                                  // step s   (even)
    if (s + 1 >= n) break;
    CONVL(z); { int t = s + 4; LOADA(b0r, t < n ? t : n - 1); }
    z = STEPM(b1r);                                  // step s+1 (odd)
    if (s + 2 >= n) break;
    CONVF(z); { int t = s + 5; LOADA(b1r, t < n ? t : n - 1); }
    z = STEPM(b2r);                                  // step s+2 (even)
    if (s + 3 >= n) break;
    CONVL(z); { int t = s + 6; LOADA(b2r, t < n ? t : n - 1); }
    z = STEPM(b3r);                                  // step s+3 (odd)
    if (s + 4 >= n) break;
    CONVF(z); { int t = s + 7; LOADA(b3r, t < n ? t : n - 1); }
    s += 4;
  }

  // store P = Q^T row m (cols from C/D reg map); regs 12..15 are padding rows
  if (m < KTAG) {
    float* dst = wsP + (size_t)(b * NCHUNK + c) * MAT + m * KTAG;
    *(float4*)(dst + 4 * hd)      = make_float4(z[0], z[1], z[2],  z[3]);
    *(float4*)(dst + 8 + 4 * hd)  = make_float4(z[4], z[5], z[6],  z[7]);
    *(float4*)(dst + 16 + 4 * hd) = make_float4(z[8], z[9], z[10], z[11]);
  }
  if (lane == 0) wsE[b * NCHUNK + c] = E;
}

// ---------------------------------------------------------------------------
// Phase B (MFMA) + fused final sum: one wave per batch folds chunk matrices
// as a matrix chain T <- P_c^T * T (R9/R10-verified math); after writing
// wsR[b], the LAST block (counter) reduces wsR -> out. Counter pattern
// proven correct in R11; confined here to the tiny kernel so its fences
// cannot disturb the BW-heavy phase A.
// ---------------------------------------------------------------------------
__global__ __launch_bounds__(64) void chainmat_kernel(
    const float* __restrict__ scores, const int* __restrict__ targets,
    const float* __restrict__ wsP, const int* __restrict__ wsE,
    const float* __restrict__ wsG, const int* __restrict__ lengths,
    float* __restrict__ wsR, int* __restrict__ cnt, float* __restrict__ out)
{
  const int b = blockIdx.x;
  const int lane = threadIdx.x;
  const int hd = lane >> 5;
  const int m = lane & 31;
  const int mc = m < KTAG ? m : KTAG - 1;
  const int len = lengths[b];
  const int nc = (len + 30) >> 5;        // ceil((len-1)/32); live chunks
  const float* sb = scores + (size_t)b * T_LEN * MAT;

  const float g0 = sb[targets[b * T_LEN]];

  if (nc == 0) {                         // len == 1: logZ = s[0][START][END]
    if (lane == 0) wsR[b] = sb[START_TAG * KTAG + END_TAG] - g0;
  } else {
    float gv = 0.f;
    if (lane < nc) gv = wsG[b * NCHUNK + lane];
    #pragma unroll
    for (int off = 1; off < 64; off <<= 1) gv += __shfl_xor(gv, off, 64);

    int ev = 0;
    if (lane < nc) ev = wsE[b * NCHUNK + lane];
    #pragma unroll
    for (int off = 1; off < 64; off <<= 1) ev += __shfl_xor(ev, off, 64);
    int E = ev;

    int off1[8], off2[4];
    #pragma unroll
    for (int e = 0; e < 8; ++e) {
      int k = (e & 3) + 8 * (e >> 2) + 4 * hd;
      off1[e] = k * KTAG + mc;
    }
    #pragma unroll
    for (int e = 0; e < 4; ++e) {
      int k = 16 + e + 4 * hd;
      off2[e] = k * KTAG + mc;
    }
    const float* pbase = wsP + (size_t)b * NCHUNK * MAT;

    float f0[12], f1[12];
    auto LOADP = [&](float (&buf)[12], int c) {
      const float* pb = pbase + (size_t)c * MAT;
      #pragma unroll
      for (int e = 0; e < 8; ++e) buf[e] = pb[off1[e]];
      #pragma unroll
      for (int e = 0; e < 4; ++e) buf[8 + e] = pb[off2[e]];
    };

    unsigned int p[8];
    #pragma unroll
    for (int r = 0; r < 8; ++r) {
      int rlo = ((2 * r) & 3) + 8 * ((2 * r) >> 2) + 4 * hd;
      unsigned int v = 0;
      if (m == rlo)     v |= 0x3F80u;
      if (m == rlo + 1) v |= (0x3F80u << 16);
      p[r] = v;
    }

    auto STEPP = [&](const float (&buf)[12]) -> f32x16 {
      bf16x8 a1, a2;
      #pragma unroll
      for (int e = 0; e < 8; ++e) a1[e] = (short)f2bf(buf[e]);
      #pragma unroll
      for (int e = 0; e < 4; ++e) a2[e] = (short)f2bf(buf[8 + e]);
      #pragma unroll
      for (int e = 4; e < 8; ++e) a2[e] = 0;
      union { unsigned int u[4]; bf16x8 v; } B1, B2;
      B1.u[0] = p[0]; B1.u[1] = p[1]; B1.u[2] = p[2]; B1.u[3] = p[3];
      B2.u[0] = p[4]; B2.u[1] = p[5]; B2.u[2] = p[6]; B2.u[3] = p[7];
      f32x16 d = {};
      d = __builtin_amdgcn_mfma_f32_32x32x16_bf16(a1, B1.v, d, 0, 0, 0);
      d = __builtin_amdgcn_mfma_f32_32x32x16_bf16(a2, B2.v, d, 0, 0, 0);
      return d;
    };
    auto CONVP = [&](const f32x16& d) {
      int rb = __builtin_amdgcn_readfirstlane(__float_as_int(d[0]));
      int dd = ((rb >> 23) & 255) - 127;
      E += dd;
      float sc = __int_as_float((127 - dd) << 23);
      #pragma unroll
      for (int r = 0; r < 8; ++r)
        p[r] = (f2bf(d[2 * r + 1] * sc) << 16) | f2bf(d[2 * r] * sc);
    };

    LOADP(f0, 0);
    LOADP(f1, nc > 1 ? 1 : 0);
    f32x16 z;
    int c = 0;
    for (;;) {
      z = STEPP(f0);
      if (c + 1 >= nc) break;
      CONVP(z); { int t = c + 2; LOADP(f0, t < nc ? t : nc - 1); }
      z = STEPP(f1);
      if (c + 2 >= nc) break;
      CONVP(z); { int t = c + 3; LOADP(f1, t < nc ? t : nc - 1); }
      c += 2;
    }

    float tau0 = fexp2(sb[START_TAG * KTAG + mc] * LOG2E);
    float v = (hd == 1 && m < KTAG) ? z[11] * tau0 : 0.f;
    #pragma unroll
    for (int off = 1; off < 64; off <<= 1) v += __shfl_xor(v, off, 64);
    if (lane == 0) {
      float logZ = ((float)E + flog2(v)) * LN2;
      wsR[b] = logZ - gv - g0;
    }
  }

  // fused final sum: last block reduces wsR -> out (deterministic)
  __threadfence();
  int old = 0;
  if (lane == 0) old = atomicAdd(cnt, 1);
  old = __shfl(old, 0, 64);
  if (old != BATCH - 1) return;
  __threadfence();
  float v = wsR[lane] + wsR[lane + 64];
  #pragma unroll
  for (int off = 1; off < 64; off <<= 1) v += __shfl_xor(v, off, 64);
  if (lane == 0) out[0] = v * (1.0f / (float)BATCH);
}

// ---------------------------------------------------------------------------
// Fallback path (R2-verified sequential FB) — only if ws_size too small.
// ---------------------------------------------------------------------------
template<int DIR>
__device__ __forceinline__ int run_chain(const float* __restrict__ base, int len, int n,
                                         volatile float* __restrict__ tau,
                                         int lane, int h, int jj)
{
  int E = 0;
  float ref = 1.0f;
  float A[12], B[12], Cb[12];
  auto LOAD = [&](float (&buf)[12], int i) {
    if (DIR == 0) {
      const float* p = base + (size_t)(1 + i) * MAT + h * 12 * KTAG + jj;
      #pragma unroll
      for (int k = 0; k < 12; ++k) buf[k] = p[k * KTAG];
    } else {
      const float4* p = (const float4*)(base + (size_t)(len - 1 - i) * MAT + jj * KTAG + h * 12);
      float4 x = p[0], y = p[1], z = p[2];
      buf[0]=x.x; buf[1]=x.y; buf[2]=x.z; buf[3]=x.w;
      buf[4]=y.x; buf[5]=y.y; buf[6]=y.z; buf[7]=y.w;
      buf[8]=z.x; buf[9]=z.y; buf[10]=z.z; buf[11]=z.w;
    }
  };
  auto STEP = [&](const float (&buf)[12]) {
    int rb = __builtin_amdgcn_readfirstlane(__float_as_int(ref));
    int d = ((rb >> 23) & 255) - 127;
    float sc = __int_as_float((127 - d) << 23);
    E += d;
    float w[12];
    #pragma unroll
    for (int k = 0; k < 12; ++k) w[k] = fexp2(buf[k] * LOG2E);
    const float4* tp = (const float4*)((const float*)&tau[h * 12]);
    float4 t0 = tp[0], t1 = tp[1], t2 = tp[2];
    float a0 = t0.x*w[0], a1 = t0.y*w[1], a2 = t0.z*w[2], a3 = t0.w*w[3];
    a0 = fmaf(t1.x, w[4],  a0); a1 = fmaf(t1.y, w[5],  a1);
    a2 = fmaf(t1.z, w[6],  a2); a3 = fmaf(t1.w, w[7],  a3);
    a0 = fmaf(t2.x, w[8],  a0); a1 = fmaf(t2.y, w[9],  a1);
    a2 = fmaf(t2.z, w[10], a2); a3 = fmaf(t2.w, w[11], a3);
    float part = (a0 + a1) + (a2 + a3);
    float tot = part + __shfl_xor(part, 32, 64);
    float tn = tot * sc;
    if (lane < KTAG) tau[lane] = tn;
    ref = tn;
  };
  if (n > 0) {
    LOAD(A, 0); LOAD(B, n > 1 ? 1 : 0); LOAD(Cb, n > 2 ? 2 : 0);
    int i = 0;
    while (i + 3 <= n) {
      STEP(A);  { int ii = i + 3; LOAD(A,  ii < n ? ii : n - 1); }
      STEP(B);  { int ii = i + 4; LOAD(B,  ii < n ? ii : n - 1); }
      STEP(Cb); { int ii = i + 5; LOAD(Cb, ii < n ? ii : n - 1); }
      i += 3;
    }
    if (i < n)     STEP(A);
    if (i + 1 < n) STEP(B);
  }
  return E;
}

__global__ __launch_bounds__(128) void crf_fb_kernel(
    const float* __restrict__ scores, const int* __restrict__ lengths,
    float* __restrict__ acc)
{
  __shared__ float sm[2][32];
  __shared__ int smE[2];
  const int b = blockIdx.x;
  const int tid = threadIdx.x;
  const int wid = tid >> 6;
  const int lane = tid & 63;
  const int h = lane >> 5;
  const int j = lane & 31;
  const int jj = j < KTAG ? j : KTAG - 1;
  const int len = lengths[b];
  const float* base = scores + (size_t)b * T_LEN * MAT;
  const int m = len >> 1;
  volatile float* tau = sm[wid];
  int E;
  if (wid == 0) {
    if (lane < KTAG) tau[lane] = fexp2(base[START_TAG * KTAG + lane] * LOG2E);
    E = run_chain<0>(base, len, m, tau, lane, h, jj);
  } else {
    if (lane < KTAG) tau[lane] = (lane == END_TAG) ? 1.0f : 0.0f;
    E = run_chain<1>(base, len, len - 1 - m, tau, lane, h, jj);
  }
  if (lane == 0) smE[wid] = E;
  __syncthreads();
  if (wid == 0) {
    float v = (lane < KTAG) ? sm[0][lane] * sm[1][lane] : 0.0f;
    #pragma unroll
    for (int off = 1; off < 32; off <<= 1) v += __shfl_xor(v, off, 64);
    if (lane == 0) {
      float res = ((float)(smE[0] + smE[1]) + flog2(v)) * LN2;
      atomicAdd(acc, res);
    }
  }
}

__global__ __launch_bounds__(256) void gold_kernel(
    const float* __restrict__ scores, const int* __restrict__ targets,
    const int* __restrict__ lengths, float* __restrict__ acc)
{
  const int idx = blockIdx.x * blockDim.x + threadIdx.x;
  const int b = idx >> 10;
  const int t = idx & (T_LEN - 1);
  float v = 0.f;
  if (t < lengths[b]) v = scores[(size_t)idx * MAT + targets[idx]];
  #pragma unroll
  for (int off = 1; off < 64; off <<= 1) v += __shfl_xor(v, off, 64);
  if ((threadIdx.x & 63) == 0) atomicAdd(acc, -v);
}

__global__ void finalize_kernel(const float* __restrict__ acc, float* __restrict__ out) {
  out[0] = acc[0] * (1.0f / (float)BATCH);
}

extern "C" void kernel_launch(void* const* d_in, const int* in_sizes, int n_in,
                              void* d_out, int out_size, void* d_ws, size_t ws_size,
                              hipStream_t stream) {
  const float* scores = (const float*)d_in[0];
  const int* targets  = (const int*)d_in[1];
  const int* lengths  = (const int*)d_in[2];
  float* out = (float*)d_out;

  const size_t pbytes = (size_t)BATCH * NCHUNK * MAT * sizeof(float);
  const size_t ebytes = (size_t)BATCH * NCHUNK * sizeof(int);
  const size_t gbytes = (size_t)BATCH * NCHUNK * sizeof(float);
  const size_t rbytes = (size_t)BATCH * sizeof(float);
  const size_t need = pbytes + ebytes + gbytes + rbytes + 64;

  if (ws_size >= need) {
    char* base = (char*)d_ws;
    float* wsP = (float*)base;
    int*   wsE = (int*)(base + pbytes);
    float* wsG = (float*)(base + pbytes + ebytes);
    float* wsR = (float*)(base + pbytes + ebytes + gbytes);
    int*   cnt = (int*)(base + pbytes + ebytes + gbytes + rbytes);
    hipMemsetAsync(cnt, 0, 64, stream);
    chunkprod_kernel<<<BATCH * NCHUNK / 4, 256, 0, stream>>>(scores, targets, lengths,
                                                             wsP, wsE, wsG);
    chainmat_kernel<<<BATCH, 64, 0, stream>>>(scores, targets, wsP, wsE, wsG,
                                              lengths, wsR, cnt, out);
  } else {
    float* acc = (float*)d_ws;
    hipMemsetAsync(acc, 0, sizeof(float), stream);
    gold_kernel<<<BATCH * T_LEN / 256, 256, 0, stream>>>(scores, targets, lengths, acc);
    crf_fb_kernel<<<BATCH, 128, 0, stream>>>(scores, lengths, acc);
    finalize_kernel<<<1, 1, 0, stream>>>(acc, out);
  }
}

// Round 16
// 55.631 us; speedup vs baseline: 1.1107x; 1.1107x over previous
//
#include <hip/hip_runtime.h>

static constexpr int T_LEN = 1024;
static constexpr int KTAG = 24;
static constexpr int MAT = 576;      // 24*24
static constexpr int START_TAG = 22;
static constexpr int END_TAG = 23;
static constexpr int BATCH = 128;
static constexpr int CHUNK = 32;     // time steps per chunk
static constexpr int NCHUNK = 32;

static constexpr float LOG2E = 1.4426950408889634f;
static constexpr float LN2   = 0.6931471805599453f;

typedef short  bf16x8 __attribute__((ext_vector_type(8)));
typedef float  f32x16 __attribute__((ext_vector_type(16)));

__device__ __forceinline__ float fexp2(float x) { return __builtin_amdgcn_exp2f(x); }
__device__ __forceinline__ float flog2(float x) { return __builtin_amdgcn_logf(x); }

// fp32 -> bf16 bits, round-to-nearest-even (branchless; inputs finite positive).
// NOTE: hand-written v_cvt_pk_bf16_f32 asm was convicted of the R5/R6 NaNs — keep f2bf.
__device__ __forceinline__ unsigned int f2bf(float x) {
  unsigned int u = __float_as_uint(x);
  u += 0x7FFFu + ((u >> 16) & 1u);
  return u >> 16;
}

// ---------------------------------------------------------------------------
// R15 = exact R10 configuration (measured optimum, 55.1 us).
// Falsified alternatives (kept OUT by evidence): in-kernel fence/atomic fusion
// (R11: HBM collapsed to 450 GB/s); CHUNK=16 (R12: +11 us); LDS-streamed
// staging (R13: +5 us); rescale-cadence + fused sum (R14: +6.7 us).
//
// Phase A (MFMA): per-(batch,chunk) wave computes Q = W_{t0+n-1}^T ... W_{t0}^T
// via pairs of mfma_f32_32x32x16_bf16, state Q as B-operand (verified k-slot
// permutation: slot(hd,e) -> k=(e&3)+8*(e>>2)+4*hd, +16 for mfma2).
// ANTITHETIC PAIRS: lengths sorted so len[b]+len[127-b] ~= 1025; pairing
// (b,c) with (127-b,31-c) makes each wave-pair's step count ~32 constant.
// Pack-time exact 2^-dd rescale; gold partial fused into wsG slots.
// ---------------------------------------------------------------------------
__global__ __launch_bounds__(256) void chunkprod_kernel(
    const float* __restrict__ scores, const int* __restrict__ targets,
    const int* __restrict__ lengths,
    float* __restrict__ wsP, int* __restrict__ wsE, float* __restrict__ wsG)
{
  const int widx = threadIdx.x >> 6;
  const int lane = threadIdx.x & 63;
  const int i = blockIdx.x * 4 + widx;
  const int pr = i >> 1;                 // pair id
  const int anti = i & 1;
  const int b0i = pr >> 4;
  const int c0i = pr & 15;
  const int b = anti ? (127 - b0i) : b0i;
  const int c = anti ? (31 - c0i) : c0i;
  const int len = lengths[b];
  const int t0 = 1 + c * CHUNK;
  if (t0 >= len) return;                 // wave-uniform exit; slot never read
  const int n = min(CHUNK, len - t0);
  const int hd = lane >> 5;
  const int m = lane & 31;
  const int mc = m < KTAG ? m : KTAG - 1;   // address clamp for padding rows
  const float* sb = scores + (size_t)b * T_LEN * MAT;

  // fused gold partial: t in [t0, t0+n) -> wsG slot (no atomic)
  {
    float gs = 0.f;
    if (lane < n) {
      int t = t0 + lane;
      gs = sb[(size_t)t * MAT + targets[b * T_LEN + t]];
    }
    #pragma unroll
    for (int off = 1; off < 64; off <<= 1) gs += __shfl_xor(gs, off, 64);
    if (lane == 0) wsG[b * NCHUNK + c] = gs;
  }

  // A-load offsets (dwords) under the k-permutation
  int off1[8], off2[4];
  #pragma unroll
  for (int e = 0; e < 8; ++e) {
    int k = (e & 3) + 8 * (e >> 2) + 4 * hd;         // mfma1 global k
    off1[e] = k * KTAG + mc;
  }
  #pragma unroll
  for (int e = 0; e < 4; ++e) {
    int k = 16 + e + 4 * hd;                         // mfma2 global k (<24)
    off2[e] = k * KTAG + mc;
  }

  float b0r[12], b1r[12], b2r[12], b3r[12];
  auto LOADA = [&](float (&buf)[12], int step) {
    const float* pb = sb + (size_t)(t0 + step) * MAT;
    #pragma unroll
    for (int e = 0; e < 8; ++e) buf[e] = pb[off1[e]];
    #pragma unroll
    for (int e = 0; e < 4; ++e) buf[8 + e] = pb[off2[e]];
  };

  // B state: 8 packed uints (2 bf16 each). Init = identity under g().
  unsigned int p[8];
  #pragma unroll
  for (int r = 0; r < 8; ++r) {
    int rlo = ((2 * r) & 3) + 8 * ((2 * r) >> 2) + 4 * hd;  // rows (rlo, rlo+1)
    unsigned int v = 0;
    if (m == rlo)     v |= 0x3F80u;
    if (m == rlo + 1) v |= (0x3F80u << 16);
    p[r] = v;
  }

  int E = 0;

  auto STEPM = [&](const float (&buf)[12]) -> f32x16 {
    float av[12];
    #pragma unroll
    for (int i2 = 0; i2 < 12; ++i2) av[i2] = fexp2(buf[i2] * LOG2E);  // loads-only dep
    bf16x8 a1, a2;
    #pragma unroll
    for (int e = 0; e < 8; ++e) a1[e] = (short)f2bf(av[e]);
    #pragma unroll
    for (int e = 0; e < 4; ++e) a2[e] = (short)f2bf(av[8 + e]);
    #pragma unroll
    for (int e = 4; e < 8; ++e) a2[e] = 0;                   // k>=24 padding
    union { unsigned int u[4]; bf16x8 v; } B1, B2;
    B1.u[0] = p[0]; B1.u[1] = p[1]; B1.u[2] = p[2]; B1.u[3] = p[3];
    B2.u[0] = p[4]; B2.u[1] = p[5]; B2.u[2] = p[6]; B2.u[3] = p[7];
    f32x16 d = {};
    d = __builtin_amdgcn_mfma_f32_32x32x16_bf16(a1, B1.v, d, 0, 0, 0);
    d = __builtin_amdgcn_mfma_f32_32x32x16_bf16(a2, B2.v, d, 0, 0, 0);
    return d;
  };

  auto CONV = [&](const f32x16& d) {      // D -> next B with exact 2^-dd rescale
    int rb = __builtin_amdgcn_readfirstlane(__float_as_int(d[0]));
    int dd = ((rb >> 23) & 255) - 127;
    E += dd;
    float sc = __int_as_float((127 - dd) << 23);
    #pragma unroll
    for (int r = 0; r < 8; ++r)
      p[r] = (f2bf(d[2 * r + 1] * sc) << 16) | f2bf(d[2 * r] * sc);
  };

  LOADA(b0r, 0);
  LOADA(b1r, n > 1 ? 1 : 0);
  LOADA(b2r, n > 2 ? 2 : 0);
  LOADA(b3r, n > 3 ? 3 : 0);
  f32x16 z;
  int s = 0;
  for (;;) {
    z = STEPM(b0r);                                  // step s
    if (s + 1 >= n) break;
    CONV(z); { int t = s + 4; LOADA(b0r, t < n ? t : n - 1); }
    z = STEPM(b1r);                                  // step s+1
    if (s + 2 >= n) break;
    CONV(z); { int t = s + 5; LOADA(b1r, t < n ? t : n - 1); }
    z = STEPM(b2r);                                  // step s+2
    if (s + 3 >= n) break;
    CONV(z); { int t = s + 6; LOADA(b2r, t < n ? t : n - 1); }
    z = STEPM(b3r);                                  // step s+3
    if (s + 4 >= n) break;
    CONV(z); { int t = s + 7; LOADA(b3r, t < n ? t : n - 1); }
    s += 4;
  }

  // store P = Q^T row m (cols from C/D reg map); regs 12..15 are padding rows
  if (m < KTAG) {
    float* dst = wsP + (size_t)(b * NCHUNK + c) * MAT + m * KTAG;
    *(float4*)(dst + 4 * hd)      = make_float4(z[0], z[1], z[2],  z[3]);
    *(float4*)(dst + 8 + 4 * hd)  = make_float4(z[4], z[5], z[6],  z[7]);
    *(float4*)(dst + 16 + 4 * hd) = make_float4(z[8], z[9], z[10], z[11]);
  }
  if (lane == 0) wsE[b * NCHUNK + c] = E;
}

// ---------------------------------------------------------------------------
// Phase B (MFMA): one wave per batch folds chunk matrices as a matrix chain
// T <- P_c^T * T (same machinery, A from wsP, no exp2, no LDS). Final:
// tau_fin[END] = sum_i T[23][i]*tau0[i]; row 23 = z[11] @ hd=1.
// ---------------------------------------------------------------------------
__global__ __launch_bounds__(64) void chainmat_kernel(
    const float* __restrict__ scores, const int* __restrict__ targets,
    const float* __restrict__ wsP, const int* __restrict__ wsE,
    const float* __restrict__ wsG, const int* __restrict__ lengths,
    float* __restrict__ wsR)
{
  const int b = blockIdx.x;
  const int lane = threadIdx.x;
  const int hd = lane >> 5;
  const int m = lane & 31;
  const int mc = m < KTAG ? m : KTAG - 1;
  const int len = lengths[b];
  const int nc = (len + 30) >> 5;        // live chunks; dead slots never read
  const float* sb = scores + (size_t)b * T_LEN * MAT;

  // gold: chunk partials + t=0 term
  float gv = 0.f;
  if (lane < nc) gv = wsG[b * NCHUNK + lane];
  #pragma unroll
  for (int off = 1; off < 64; off <<= 1) gv += __shfl_xor(gv, off, 64);
  const float g0 = sb[targets[b * T_LEN]];

  if (nc == 0) {                         // len == 1: logZ = s[0][START][END]
    if (lane == 0) wsR[b] = sb[START_TAG * KTAG + END_TAG] - g0;
    return;
  }

  int ev = 0;
  if (lane < nc) ev = wsE[b * NCHUNK + lane];
  #pragma unroll
  for (int off = 1; off < 64; off <<= 1) ev += __shfl_xor(ev, off, 64);
  int E = ev;

  int off1[8], off2[4];
  #pragma unroll
  for (int e = 0; e < 8; ++e) {
    int k = (e & 3) + 8 * (e >> 2) + 4 * hd;
    off1[e] = k * KTAG + mc;
  }
  #pragma unroll
  for (int e = 0; e < 4; ++e) {
    int k = 16 + e + 4 * hd;
    off2[e] = k * KTAG + mc;
  }
  const float* pbase = wsP + (size_t)b * NCHUNK * MAT;

  float b0[12], b1[12];
  auto LOADP = [&](float (&buf)[12], int c) {
    const float* pb = pbase + (size_t)c * MAT;
    #pragma unroll
    for (int e = 0; e < 8; ++e) buf[e] = pb[off1[e]];
    #pragma unroll
    for (int e = 0; e < 4; ++e) buf[8 + e] = pb[off2[e]];
  };

  unsigned int p[8];
  #pragma unroll
  for (int r = 0; r < 8; ++r) {
    int rlo = ((2 * r) & 3) + 8 * ((2 * r) >> 2) + 4 * hd;
    unsigned int v = 0;
    if (m == rlo)     v |= 0x3F80u;
    if (m == rlo + 1) v |= (0x3F80u << 16);
    p[r] = v;
  }

  auto STEPP = [&](const float (&buf)[12]) -> f32x16 {
    bf16x8 a1, a2;
    #pragma unroll
    for (int e = 0; e < 8; ++e) a1[e] = (short)f2bf(buf[e]);
    #pragma unroll
    for (int e = 0; e < 4; ++e) a2[e] = (short)f2bf(buf[8 + e]);
    #pragma unroll
    for (int e = 4; e < 8; ++e) a2[e] = 0;
    union { unsigned int u[4]; bf16x8 v; } B1, B2;
    B1.u[0] = p[0]; B1.u[1] = p[1]; B1.u[2] = p[2]; B1.u[3] = p[3];
    B2.u[0] = p[4]; B2.u[1] = p[5]; B2.u[2] = p[6]; B2.u[3] = p[7];
    f32x16 d = {};
    d = __builtin_amdgcn_mfma_f32_32x32x16_bf16(a1, B1.v, d, 0, 0, 0);
    d = __builtin_amdgcn_mfma_f32_32x32x16_bf16(a2, B2.v, d, 0, 0, 0);
    return d;
  };
  auto CONVP = [&](const f32x16& d) {
    int rb = __builtin_amdgcn_readfirstlane(__float_as_int(d[0]));
    int dd = ((rb >> 23) & 255) - 127;
    E += dd;
    float sc = __int_as_float((127 - dd) << 23);
    #pragma unroll
    for (int r = 0; r < 8; ++r)
      p[r] = (f2bf(d[2 * r + 1] * sc) << 16) | f2bf(d[2 * r] * sc);
  };

  LOADP(b0, 0);
  LOADP(b1, nc > 1 ? 1 : 0);
  f32x16 z;
  int c = 0;
  for (;;) {
    z = STEPP(b0);
    if (c + 1 >= nc) break;
    CONVP(z); { int t = c + 2; LOADP(b0, t < nc ? t : nc - 1); }
    z = STEPP(b1);
    if (c + 2 >= nc) break;
    CONVP(z); { int t = c + 3; LOADP(b1, t < nc ? t : nc - 1); }
    c += 2;
  }

  // tau_fin[END] = sum_i z[11](hd=1, m=i) * tau0[i]
  float tau0 = fexp2(sb[START_TAG * KTAG + mc] * LOG2E);
  float v = (hd == 1 && m < KTAG) ? z[11] * tau0 : 0.f;
  #pragma unroll
  for (int off = 1; off < 64; off <<= 1) v += __shfl_xor(v, off, 64);
  if (lane == 0) {
    float logZ = ((float)E + flog2(v)) * LN2;
    wsR[b] = logZ - gv - g0;
  }
}

__global__ __launch_bounds__(64) void sum_kernel(
    const float* __restrict__ wsR, float* __restrict__ out)
{
  const int lane = threadIdx.x;
  float v = wsR[lane] + wsR[lane + 64];
  #pragma unroll
  for (int off = 1; off < 64; off <<= 1) v += __shfl_xor(v, off, 64);
  if (lane == 0) out[0] = v * (1.0f / (float)BATCH);
}

// ---------------------------------------------------------------------------
// Fallback path (R2-verified sequential FB) — only if ws_size too small.
// ---------------------------------------------------------------------------
template<int DIR>
__device__ __forceinline__ int run_chain(const float* __restrict__ base, int len, int n,
                                         volatile float* __restrict__ tau,
                                         int lane, int h, int jj)
{
  int E = 0;
  float ref = 1.0f;
  float A[12], B[12], Cb[12];
  auto LOAD = [&](float (&buf)[12], int i) {
    if (DIR == 0) {
      const float* p = base + (size_t)(1 + i) * MAT + h * 12 * KTAG + jj;
      #pragma unroll
      for (int k = 0; k < 12; ++k) buf[k] = p[k * KTAG];
    } else {
      const float4* p = (const float4*)(base + (size_t)(len - 1 - i) * MAT + jj * KTAG + h * 12);
      float4 x = p[0], y = p[1], z = p[2];
      buf[0]=x.x; buf[1]=x.y; buf[2]=x.z; buf[3]=x.w;
      buf[4]=y.x; buf[5]=y.y; buf[6]=y.z; buf[7]=y.w;
      buf[8]=z.x; buf[9]=z.y; buf[10]=z.z; buf[11]=z.w;
    }
  };
  auto STEP = [&](const float (&buf)[12]) {
    int rb = __builtin_amdgcn_readfirstlane(__float_as_int(ref));
    int d = ((rb >> 23) & 255) - 127;
    float sc = __int_as_float((127 - d) << 23);
    E += d;
    float w[12];
    #pragma unroll
    for (int k = 0; k < 12; ++k) w[k] = fexp2(buf[k] * LOG2E);
    const float4* tp = (const float4*)((const float*)&tau[h * 12]);
    float4 t0 = tp[0], t1 = tp[1], t2 = tp[2];
    float a0 = t0.x*w[0], a1 = t0.y*w[1], a2 = t0.z*w[2], a3 = t0.w*w[3];
    a0 = fmaf(t1.x, w[4],  a0); a1 = fmaf(t1.y, w[5],  a1);
    a2 = fmaf(t1.z, w[6],  a2); a3 = fmaf(t1.w, w[7],  a3);
    a0 = fmaf(t2.x, w[8],  a0); a1 = fmaf(t2.y, w[9],  a1);
    a2 = fmaf(t2.z, w[10], a2); a3 = fmaf(t2.w, w[11], a3);
    float part = (a0 + a1) + (a2 + a3);
    float tot = part + __shfl_xor(part, 32, 64);
    float tn = tot * sc;
    if (lane < KTAG) tau[lane] = tn;
    ref = tn;
  };
  if (n > 0) {
    LOAD(A, 0); LOAD(B, n > 1 ? 1 : 0); LOAD(Cb, n > 2 ? 2 : 0);
    int i = 0;
    while (i + 3 <= n) {
      STEP(A);  { int ii = i + 3; LOAD(A,  ii < n ? ii : n - 1); }
      STEP(B);  { int ii = i + 4; LOAD(B,  ii < n ? ii : n - 1); }
      STEP(Cb); { int ii = i + 5; LOAD(Cb, ii < n ? ii : n - 1); }
      i += 3;
    }
    if (i < n)     STEP(A);
    if (i + 1 < n) STEP(B);
  }
  return E;
}

__global__ __launch_bounds__(128) void crf_fb_kernel(
    const float* __restrict__ scores, const int* __restrict__ lengths,
    float* __restrict__ acc)
{
  __shared__ float sm[2][32];
  __shared__ int smE[2];
  const int b = blockIdx.x;
  const int tid = threadIdx.x;
  const int wid = tid >> 6;
  const int lane = tid & 63;
  const int h = lane >> 5;
  const int j = lane & 31;
  const int jj = j < KTAG ? j : KTAG - 1;
  const int len = lengths[b];
  const float* base = scores + (size_t)b * T_LEN * MAT;
  const int m = len >> 1;
  volatile float* tau = sm[wid];
  int E;
  if (wid == 0) {
    if (lane < KTAG) tau[lane] = fexp2(base[START_TAG * KTAG + lane] * LOG2E);
    E = run_chain<0>(base, len, m, tau, lane, h, jj);
  } else {
    if (lane < KTAG) tau[lane] = (lane == END_TAG) ? 1.0f : 0.0f;
    E = run_chain<1>(base, len, len - 1 - m, tau, lane, h, jj);
  }
  if (lane == 0) smE[wid] = E;
  __syncthreads();
  if (wid == 0) {
    float v = (lane < KTAG) ? sm[0][lane] * sm[1][lane] : 0.0f;
    #pragma unroll
    for (int off = 1; off < 32; off <<= 1) v += __shfl_xor(v, off, 64);
    if (lane == 0) {
      float res = ((float)(smE[0] + smE[1]) + flog2(v)) * LN2;
      atomicAdd(acc, res);
    }
  }
}

__global__ __launch_bounds__(256) void gold_kernel(
    const float* __restrict__ scores, const int* __restrict__ targets,
    const int* __restrict__ lengths, float* __restrict__ acc)
{
  const int idx = blockIdx.x * blockDim.x + threadIdx.x;
  const int b = idx >> 10;
  const int t = idx & (T_LEN - 1);
  float v = 0.f;
  if (t < lengths[b]) v = scores[(size_t)idx * MAT + targets[idx]];
  #pragma unroll
  for (int off = 1; off < 64; off <<= 1) v += __shfl_xor(v, off, 64);
  if ((threadIdx.x & 63) == 0) atomicAdd(acc, -v);
}

__global__ void finalize_kernel(const float* __restrict__ acc, float* __restrict__ out) {
  out[0] = acc[0] * (1.0f / (float)BATCH);
}

extern "C" void kernel_launch(void* const* d_in, const int* in_sizes, int n_in,
                              void* d_out, int out_size, void* d_ws, size_t ws_size,
                              hipStream_t stream) {
  const float* scores = (const float*)d_in[0];
  const int* targets  = (const int*)d_in[1];
  const int* lengths  = (const int*)d_in[2];
  float* out = (float*)d_out;

  const size_t pbytes = (size_t)BATCH * NCHUNK * MAT * sizeof(float);
  const size_t ebytes = (size_t)BATCH * NCHUNK * sizeof(int);
  const size_t gbytes = (size_t)BATCH * NCHUNK * sizeof(float);
  const size_t need = pbytes + ebytes + gbytes + BATCH * sizeof(float);

  if (ws_size >= need) {
    float* wsP = (float*)d_ws;
    int*   wsE = (int*)((char*)d_ws + pbytes);
    float* wsG = (float*)((char*)d_ws + pbytes + ebytes);
    float* wsR = (float*)((char*)d_ws + pbytes + ebytes + gbytes);
    chunkprod_kernel<<<BATCH * NCHUNK / 4, 256, 0, stream>>>(scores, targets, lengths,
                                                             wsP, wsE, wsG);
    chainmat_kernel<<<BATCH, 64, 0, stream>>>(scores, targets, wsP, wsE, wsG,
                                              lengths, wsR);
    sum_kernel<<<1, 64, 0, stream>>>(wsR, out);
  } else {
    float* acc = (float*)d_ws;
    hipMemsetAsync(acc, 0, sizeof(float), stream);
    gold_kernel<<<BATCH * T_LEN / 256, 256, 0, stream>>>(scores, targets, lengths, acc);
    crf_fb_kernel<<<BATCH, 128, 0, stream>>>(scores, lengths, acc);
    finalize_kernel<<<1, 1, 0, stream>>>(acc, out);
  }
}

// Round 17
// 55.530 us; speedup vs baseline: 1.1127x; 1.0018x over previous
//
#include <hip/hip_runtime.h>

static constexpr int T_LEN = 1024;
static constexpr int KTAG = 24;
static constexpr int MAT = 576;      // 24*24
static constexpr int START_TAG = 22;
static constexpr int END_TAG = 23;
static constexpr int BATCH = 128;
static constexpr int CHUNK = 32;     // time steps per chunk
static constexpr int NCHUNK = 32;

static constexpr float LOG2E = 1.4426950408889634f;
static constexpr float LN2   = 0.6931471805599453f;

typedef short  bf16x8 __attribute__((ext_vector_type(8)));
typedef float  f32x16 __attribute__((ext_vector_type(16)));

__device__ __forceinline__ float fexp2(float x) { return __builtin_amdgcn_exp2f(x); }
__device__ __forceinline__ float flog2(float x) { return __builtin_amdgcn_logf(x); }

// fp32 -> bf16 bits, round-to-nearest-even (branchless; inputs finite positive).
// NOTE: hand-written v_cvt_pk_bf16_f32 asm was convicted of the R5/R6 NaNs — keep f2bf.
__device__ __forceinline__ unsigned int f2bf(float x) {
  unsigned int u = __float_as_uint(x);
  u += 0x7FFFu + ((u >> 16) & 1u);
  return u >> 16;
}

// ---------------------------------------------------------------------------
// R16 = R15/R10 kernel with ONE change: chunkprod block 256->128 threads
// (one antithetic pair per block; 2048 blocks). At ~72 VGPR the wave/CU cap
// is 16; 256-thread blocks quantized to 3 blocks/CU = 12 waves/CU, while
// 128-thread blocks reach 8 blocks/CU = 16 waves/CU (+33% latency hiding).
// Work/numerics byte-identical to the verified 55.1us configuration.
// Falsified & kept out: in-kernel fence fusion (R11), CHUNK=16 (R12),
// LDS streaming (R13), rescale cadence + fused sum (R14).
// ---------------------------------------------------------------------------
__global__ __launch_bounds__(128) void chunkprod_kernel(
    const float* __restrict__ scores, const int* __restrict__ targets,
    const int* __restrict__ lengths,
    float* __restrict__ wsP, int* __restrict__ wsE, float* __restrict__ wsG)
{
  const int widx = threadIdx.x >> 6;     // 0..1: the two halves of one pair
  const int lane = threadIdx.x & 63;
  const int i = blockIdx.x * 2 + widx;
  const int pr = i >> 1;                 // pair id
  const int anti = i & 1;
  const int b0i = pr >> 4;
  const int c0i = pr & 15;
  const int b = anti ? (127 - b0i) : b0i;
  const int c = anti ? (31 - c0i) : c0i;
  const int len = lengths[b];
  const int t0 = 1 + c * CHUNK;
  if (t0 >= len) return;                 // wave-uniform exit; slot never read
  const int n = min(CHUNK, len - t0);
  const int hd = lane >> 5;
  const int m = lane & 31;
  const int mc = m < KTAG ? m : KTAG - 1;   // address clamp for padding rows
  const float* sb = scores + (size_t)b * T_LEN * MAT;

  // fused gold partial: t in [t0, t0+n) -> wsG slot (no atomic)
  {
    float gs = 0.f;
    if (lane < n) {
      int t = t0 + lane;
      gs = sb[(size_t)t * MAT + targets[b * T_LEN + t]];
    }
    #pragma unroll
    for (int off = 1; off < 64; off <<= 1) gs += __shfl_xor(gs, off, 64);
    if (lane == 0) wsG[b * NCHUNK + c] = gs;
  }

  // A-load offsets (dwords) under the k-permutation
  int off1[8], off2[4];
  #pragma unroll
  for (int e = 0; e < 8; ++e) {
    int k = (e & 3) + 8 * (e >> 2) + 4 * hd;         // mfma1 global k
    off1[e] = k * KTAG + mc;
  }
  #pragma unroll
  for (int e = 0; e < 4; ++e) {
    int k = 16 + e + 4 * hd;                         // mfma2 global k (<24)
    off2[e] = k * KTAG + mc;
  }

  float b0r[12], b1r[12], b2r[12], b3r[12];
  auto LOADA = [&](float (&buf)[12], int step) {
    const float* pb = sb + (size_t)(t0 + step) * MAT;
    #pragma unroll
    for (int e = 0; e < 8; ++e) buf[e] = pb[off1[e]];
    #pragma unroll
    for (int e = 0; e < 4; ++e) buf[8 + e] = pb[off2[e]];
  };

  // B state: 8 packed uints (2 bf16 each). Init = identity under g().
  unsigned int p[8];
  #pragma unroll
  for (int r = 0; r < 8; ++r) {
    int rlo = ((2 * r) & 3) + 8 * ((2 * r) >> 2) + 4 * hd;  // rows (rlo, rlo+1)
    unsigned int v = 0;
    if (m == rlo)     v |= 0x3F80u;
    if (m == rlo + 1) v |= (0x3F80u << 16);
    p[r] = v;
  }

  int E = 0;

  auto STEPM = [&](const float (&buf)[12]) -> f32x16 {
    float av[12];
    #pragma unroll
    for (int i2 = 0; i2 < 12; ++i2) av[i2] = fexp2(buf[i2] * LOG2E);  // loads-only dep
    bf16x8 a1, a2;
    #pragma unroll
    for (int e = 0; e < 8; ++e) a1[e] = (short)f2bf(av[e]);
    #pragma unroll
    for (int e = 0; e < 4; ++e) a2[e] = (short)f2bf(av[8 + e]);
    #pragma unroll
    for (int e = 4; e < 8; ++e) a2[e] = 0;                   // k>=24 padding
    union { unsigned int u[4]; bf16x8 v; } B1, B2;
    B1.u[0] = p[0]; B1.u[1] = p[1]; B1.u[2] = p[2]; B1.u[3] = p[3];
    B2.u[0] = p[4]; B2.u[1] = p[5]; B2.u[2] = p[6]; B2.u[3] = p[7];
    f32x16 d = {};
    d = __builtin_amdgcn_mfma_f32_32x32x16_bf16(a1, B1.v, d, 0, 0, 0);
    d = __builtin_amdgcn_mfma_f32_32x32x16_bf16(a2, B2.v, d, 0, 0, 0);
    return d;
  };

  auto CONV = [&](const f32x16& d) {      // D -> next B with exact 2^-dd rescale
    int rb = __builtin_amdgcn_readfirstlane(__float_as_int(d[0]));
    int dd = ((rb >> 23) & 255) - 127;
    E += dd;
    float sc = __int_as_float((127 - dd) << 23);
    #pragma unroll
    for (int r = 0; r < 8; ++r)
      p[r] = (f2bf(d[2 * r + 1] * sc) << 16) | f2bf(d[2 * r] * sc);
  };

  LOADA(b0r, 0);
  LOADA(b1r, n > 1 ? 1 : 0);
  LOADA(b2r, n > 2 ? 2 : 0);
  LOADA(b3r, n > 3 ? 3 : 0);
  f32x16 z;
  int s = 0;
  for (;;) {
    z = STEPM(b0r);                                  // step s
    if (s + 1 >= n) break;
    CONV(z); { int t = s + 4; LOADA(b0r, t < n ? t : n - 1); }
    z = STEPM(b1r);                                  // step s+1
    if (s + 2 >= n) break;
    CONV(z); { int t = s + 5; LOADA(b1r, t < n ? t : n - 1); }
    z = STEPM(b2r);                                  // step s+2
    if (s + 3 >= n) break;
    CONV(z); { int t = s + 6; LOADA(b2r, t < n ? t : n - 1); }
    z = STEPM(b3r);                                  // step s+3
    if (s + 4 >= n) break;
    CONV(z); { int t = s + 7; LOADA(b3r, t < n ? t : n - 1); }
    s += 4;
  }

  // store P = Q^T row m (cols from C/D reg map); regs 12..15 are padding rows
  if (m < KTAG) {
    float* dst = wsP + (size_t)(b * NCHUNK + c) * MAT + m * KTAG;
    *(float4*)(dst + 4 * hd)      = make_float4(z[0], z[1], z[2],  z[3]);
    *(float4*)(dst + 8 + 4 * hd)  = make_float4(z[4], z[5], z[6],  z[7]);
    *(float4*)(dst + 16 + 4 * hd) = make_float4(z[8], z[9], z[10], z[11]);
  }
  if (lane == 0) wsE[b * NCHUNK + c] = E;
}

// ---------------------------------------------------------------------------
// Phase B (MFMA): one wave per batch folds chunk matrices as a matrix chain
// T <- P_c^T * T (same machinery, A from wsP, no exp2, no LDS). Final:
// tau_fin[END] = sum_i T[23][i]*tau0[i]; row 23 = z[11] @ hd=1.
// ---------------------------------------------------------------------------
__global__ __launch_bounds__(64) void chainmat_kernel(
    const float* __restrict__ scores, const int* __restrict__ targets,
    const float* __restrict__ wsP, const int* __restrict__ wsE,
    const float* __restrict__ wsG, const int* __restrict__ lengths,
    float* __restrict__ wsR)
{
  const int b = blockIdx.x;
  const int lane = threadIdx.x;
  const int hd = lane >> 5;
  const int m = lane & 31;
  const int mc = m < KTAG ? m : KTAG - 1;
  const int len = lengths[b];
  const int nc = (len + 30) >> 5;        // live chunks; dead slots never read
  const float* sb = scores + (size_t)b * T_LEN * MAT;

  // gold: chunk partials + t=0 term
  float gv = 0.f;
  if (lane < nc) gv = wsG[b * NCHUNK + lane];
  #pragma unroll
  for (int off = 1; off < 64; off <<= 1) gv += __shfl_xor(gv, off, 64);
  const float g0 = sb[targets[b * T_LEN]];

  if (nc == 0) {                         // len == 1: logZ = s[0][START][END]
    if (lane == 0) wsR[b] = sb[START_TAG * KTAG + END_TAG] - g0;
    return;
  }

  int ev = 0;
  if (lane < nc) ev = wsE[b * NCHUNK + lane];
  #pragma unroll
  for (int off = 1; off < 64; off <<= 1) ev += __shfl_xor(ev, off, 64);
  int E = ev;

  int off1[8], off2[4];
  #pragma unroll
  for (int e = 0; e < 8; ++e) {
    int k = (e & 3) + 8 * (e >> 2) + 4 * hd;
    off1[e] = k * KTAG + mc;
  }
  #pragma unroll
  for (int e = 0; e < 4; ++e) {
    int k = 16 + e + 4 * hd;
    off2[e] = k * KTAG + mc;
  }
  const float* pbase = wsP + (size_t)b * NCHUNK * MAT;

  float b0[12], b1[12];
  auto LOADP = [&](float (&buf)[12], int c) {
    const float* pb = pbase + (size_t)c * MAT;
    #pragma unroll
    for (int e = 0; e < 8; ++e) buf[e] = pb[off1[e]];
    #pragma unroll
    for (int e = 0; e < 4; ++e) buf[8 + e] = pb[off2[e]];
  };

  unsigned int p[8];
  #pragma unroll
  for (int r = 0; r < 8; ++r) {
    int rlo = ((2 * r) & 3) + 8 * ((2 * r) >> 2) + 4 * hd;
    unsigned int v = 0;
    if (m == rlo)     v |= 0x3F80u;
    if (m == rlo + 1) v |= (0x3F80u << 16);
    p[r] = v;
  }

  auto STEPP = [&](const float (&buf)[12]) -> f32x16 {
    bf16x8 a1, a2;
    #pragma unroll
    for (int e = 0; e < 8; ++e) a1[e] = (short)f2bf(buf[e]);
    #pragma unroll
    for (int e = 0; e < 4; ++e) a2[e] = (short)f2bf(buf[8 + e]);
    #pragma unroll
    for (int e = 4; e < 8; ++e) a2[e] = 0;
    union { unsigned int u[4]; bf16x8 v; } B1, B2;
    B1.u[0] = p[0]; B1.u[1] = p[1]; B1.u[2] = p[2]; B1.u[3] = p[3];
    B2.u[0] = p[4]; B2.u[1] = p[5]; B2.u[2] = p[6]; B2.u[3] = p[7];
    f32x16 d = {};
    d = __builtin_amdgcn_mfma_f32_32x32x16_bf16(a1, B1.v, d, 0, 0, 0);
    d = __builtin_amdgcn_mfma_f32_32x32x16_bf16(a2, B2.v, d, 0, 0, 0);
    return d;
  };
  auto CONVP = [&](const f32x16& d) {
    int rb = __builtin_amdgcn_readfirstlane(__float_as_int(d[0]));
    int dd = ((rb >> 23) & 255) - 127;
    E += dd;
    float sc = __int_as_float((127 - dd) << 23);
    #pragma unroll
    for (int r = 0; r < 8; ++r)
      p[r] = (f2bf(d[2 * r + 1] * sc) << 16) | f2bf(d[2 * r] * sc);
  };

  LOADP(b0, 0);
  LOADP(b1, nc > 1 ? 1 : 0);
  f32x16 z;
  int c = 0;
  for (;;) {
    z = STEPP(b0);
    if (c + 1 >= nc) break;
    CONVP(z); { int t = c + 2; LOADP(b0, t < nc ? t : nc - 1); }
    z = STEPP(b1);
    if (c + 2 >= nc) break;
    CONVP(z); { int t = c + 3; LOADP(b1, t < nc ? t : nc - 1); }
    c += 2;
  }

  // tau_fin[END] = sum_i z[11](hd=1, m=i) * tau0[i]
  float tau0 = fexp2(sb[START_TAG * KTAG + mc] * LOG2E);
  float v = (hd == 1 && m < KTAG) ? z[11] * tau0 : 0.f;
  #pragma unroll
  for (int off = 1; off < 64; off <<= 1) v += __shfl_xor(v, off, 64);
  if (lane == 0) {
    float logZ = ((float)E + flog2(v)) * LN2;
    wsR[b] = logZ - gv - g0;
  }
}

__global__ __launch_bounds__(64) void sum_kernel(
    const float* __restrict__ wsR, float* __restrict__ out)
{
  const int lane = threadIdx.x;
  float v = wsR[lane] + wsR[lane + 64];
  #pragma unroll
  for (int off = 1; off < 64; off <<= 1) v += __shfl_xor(v, off, 64);
  if (lane == 0) out[0] = v * (1.0f / (float)BATCH);
}

// ---------------------------------------------------------------------------
// Fallback path (R2-verified sequential FB) — only if ws_size too small.
// ---------------------------------------------------------------------------
template<int DIR>
__device__ __forceinline__ int run_chain(const float* __restrict__ base, int len, int n,
                                         volatile float* __restrict__ tau,
                                         int lane, int h, int jj)
{
  int E = 0;
  float ref = 1.0f;
  float A[12], B[12], Cb[12];
  auto LOAD = [&](float (&buf)[12], int i) {
    if (DIR == 0) {
      const float* p = base + (size_t)(1 + i) * MAT + h * 12 * KTAG + jj;
      #pragma unroll
      for (int k = 0; k < 12; ++k) buf[k] = p[k * KTAG];
    } else {
      const float4* p = (const float4*)(base + (size_t)(len - 1 - i) * MAT + jj * KTAG + h * 12);
      float4 x = p[0], y = p[1], z = p[2];
      buf[0]=x.x; buf[1]=x.y; buf[2]=x.z; buf[3]=x.w;
      buf[4]=y.x; buf[5]=y.y; buf[6]=y.z; buf[7]=y.w;
      buf[8]=z.x; buf[9]=z.y; buf[10]=z.z; buf[11]=z.w;
    }
  };
  auto STEP = [&](const float (&buf)[12]) {
    int rb = __builtin_amdgcn_readfirstlane(__float_as_int(ref));
    int d = ((rb >> 23) & 255) - 127;
    float sc = __int_as_float((127 - d) << 23);
    E += d;
    float w[12];
    #pragma unroll
    for (int k = 0; k < 12; ++k) w[k] = fexp2(buf[k] * LOG2E);
    const float4* tp = (const float4*)((const float*)&tau[h * 12]);
    float4 t0 = tp[0], t1 = tp[1], t2 = tp[2];
    float a0 = t0.x*w[0], a1 = t0.y*w[1], a2 = t0.z*w[2], a3 = t0.w*w[3];
    a0 = fmaf(t1.x, w[4],  a0); a1 = fmaf(t1.y, w[5],  a1);
    a2 = fmaf(t1.z, w[6],  a2); a3 = fmaf(t1.w, w[7],  a3);
    a0 = fmaf(t2.x, w[8],  a0); a1 = fmaf(t2.y, w[9],  a1);
    a2 = fmaf(t2.z, w[10], a2); a3 = fmaf(t2.w, w[11], a3);
    float part = (a0 + a1) + (a2 + a3);
    float tot = part + __shfl_xor(part, 32, 64);
    float tn = tot * sc;
    if (lane < KTAG) tau[lane] = tn;
    ref = tn;
  };
  if (n > 0) {
    LOAD(A, 0); LOAD(B, n > 1 ? 1 : 0); LOAD(Cb, n > 2 ? 2 : 0);
    int i = 0;
    while (i + 3 <= n) {
      STEP(A);  { int ii = i + 3; LOAD(A,  ii < n ? ii : n - 1); }
      STEP(B);  { int ii = i + 4; LOAD(B,  ii < n ? ii : n - 1); }
      STEP(Cb); { int ii = i + 5; LOAD(Cb, ii < n ? ii : n - 1); }
      i += 3;
    }
    if (i < n)     STEP(A);
    if (i + 1 < n) STEP(B);
  }
  return E;
}

__global__ __launch_bounds__(128) void crf_fb_kernel(
    const float* __restrict__ scores, const int* __restrict__ lengths,
    float* __restrict__ acc)
{
  __shared__ float sm[2][32];
  __shared__ int smE[2];
  const int b = blockIdx.x;
  const int tid = threadIdx.x;
  const int wid = tid >> 6;
  const int lane = tid & 63;
  const int h = lane >> 5;
  const int j = lane & 31;
  const int jj = j < KTAG ? j : KTAG - 1;
  const int len = lengths[b];
  const float* base = scores + (size_t)b * T_LEN * MAT;
  const int m = len >> 1;
  volatile float* tau = sm[wid];
  int E;
  if (wid == 0) {
    if (lane < KTAG) tau[lane] = fexp2(base[START_TAG * KTAG + lane] * LOG2E);
    E = run_chain<0>(base, len, m, tau, lane, h, jj);
  } else {
    if (lane < KTAG) tau[lane] = (lane == END_TAG) ? 1.0f : 0.0f;
    E = run_chain<1>(base, len, len - 1 - m, tau, lane, h, jj);
  }
  if (lane == 0) smE[wid] = E;
  __syncthreads();
  if (wid == 0) {
    float v = (lane < KTAG) ? sm[0][lane] * sm[1][lane] : 0.0f;
    #pragma unroll
    for (int off = 1; off < 32; off <<= 1) v += __shfl_xor(v, off, 64);
    if (lane == 0) {
      float res = ((float)(smE[0] + smE[1]) + flog2(v)) * LN2;
      atomicAdd(acc, res);
    }
  }
}

__global__ __launch_bounds__(256) void gold_kernel(
    const float* __restrict__ scores, const int* __restrict__ targets,
    const int* __restrict__ lengths, float* __restrict__ acc)
{
  const int idx = blockIdx.x * blockDim.x + threadIdx.x;
  const int b = idx >> 10;
  const int t = idx & (T_LEN - 1);
  float v = 0.f;
  if (t < lengths[b]) v = scores[(size_t)idx * MAT + targets[idx]];
  #pragma unroll
  for (int off = 1; off < 64; off <<= 1) v += __shfl_xor(v, off, 64);
  if ((threadIdx.x & 63) == 0) atomicAdd(acc, -v);
}

__global__ void finalize_kernel(const float* __restrict__ acc, float* __restrict__ out) {
  out[0] = acc[0] * (1.0f / (float)BATCH);
}

extern "C" void kernel_launch(void* const* d_in, const int* in_sizes, int n_in,
                              void* d_out, int out_size, void* d_ws, size_t ws_size,
                              hipStream_t stream) {
  const float* scores = (const float*)d_in[0];
  const int* targets  = (const int*)d_in[1];
  const int* lengths  = (const int*)d_in[2];
  float* out = (float*)d_out;

  const size_t pbytes = (size_t)BATCH * NCHUNK * MAT * sizeof(float);
  const size_t ebytes = (size_t)BATCH * NCHUNK * sizeof(int);
  const size_t gbytes = (size_t)BATCH * NCHUNK * sizeof(float);
  const size_t need = pbytes + ebytes + gbytes + BATCH * sizeof(float);

  if (ws_size >= need) {
    float* wsP = (float*)d_ws;
    int*   wsE = (int*)((char*)d_ws + pbytes);
    float* wsG = (float*)((char*)d_ws + pbytes + ebytes);
    float* wsR = (float*)((char*)d_ws + pbytes + ebytes + gbytes);
    chunkprod_kernel<<<BATCH * NCHUNK / 2, 128, 0, stream>>>(scores, targets, lengths,
                                                             wsP, wsE, wsG);
    chainmat_kernel<<<BATCH, 64, 0, stream>>>(scores, targets, wsP, wsE, wsG,
                                              lengths, wsR);
    sum_kernel<<<1, 64, 0, stream>>>(wsR, out);
  } else {
    float* acc = (float*)d_ws;
    hipMemsetAsync(acc, 0, sizeof(float), stream);
    gold_kernel<<<BATCH * T_LEN / 256, 256, 0, stream>>>(scores, targets, lengths, acc);
    crf_fb_kernel<<<BATCH, 128, 0, stream>>>(scores, lengths, acc);
    finalize_kernel<<<1, 1, 0, stream>>>(acc, out);
  }
}